// Round 4
// baseline (1037.265 us; speedup 1.0000x reference)
//
#include <hip/hip_runtime.h>
#include <math.h>

#define NN 50000
#define NE 640000
#define NR 8
#define KT 1152   // 8*128 (relations) + 128 (root)

typedef __attribute__((ext_vector_type(8))) _Float16 half8;
typedef __attribute__((ext_vector_type(8))) short short8;
typedef __attribute__((ext_vector_type(4))) float f32x4;
typedef const void __attribute__((address_space(1))) gvoid_t;
typedef void __attribute__((address_space(3))) svoid_t;

__device__ __forceinline__ unsigned short f2h(float f) {
    _Float16 h = (_Float16)f;                       // v_cvt_f16_f32, RNE
    return __builtin_bit_cast(unsigned short, h);
}
__device__ __forceinline__ float h2f(unsigned short u) {
    return (float)__builtin_bit_cast(_Float16, u);
}

// ---------- preprocessing ----------
__global__ __launch_bounds__(256) void count_kernel(const int* __restrict__ dst,
                                                    const int* __restrict__ typ,
                                                    int* __restrict__ cnt, int E) {
    int e = blockIdx.x * 256 + threadIdx.x;
    if (e < E) atomicAdd(&cnt[dst[e] * NR + typ[e]], 1);
}

__global__ __launch_bounds__(256) void inv_kernel(const int* __restrict__ cnt,
                                                  float* __restrict__ inv, int n) {
    int i = blockIdx.x * 256 + threadIdx.x;
    if (i < n) {
        int c = cnt[i];
        inv[i] = 1.0f / (float)(c > 1 ? c : 1);
    }
}

// single-block exclusive scan over cnt[0..n) -> rowptr[0..n]
__global__ __launch_bounds__(1024) void scan_kernel(const int* __restrict__ cnt,
                                                    int* __restrict__ rowptr, int n) {
    __shared__ int partial[1024];
    int t = threadIdx.x;
    int chunk = (n + 1023) / 1024;
    int lo = t * chunk;
    int hi = lo + chunk; if (hi > n) hi = n;
    int s = 0;
    for (int i = lo; i < hi; ++i) s += cnt[i];
    partial[t] = s;
    __syncthreads();
    for (int off = 1; off < 1024; off <<= 1) {
        int v = (t >= off) ? partial[t - off] : 0;
        __syncthreads();
        partial[t] += v;
        __syncthreads();
    }
    int run = (t == 0) ? 0 : partial[t - 1];
    for (int i = lo; i < hi; ++i) { rowptr[i] = run; run += cnt[i]; }
    if (t == 0) rowptr[n] = partial[1023];
}

__global__ __launch_bounds__(256) void copy_kernel(const int* __restrict__ a,
                                                   int* __restrict__ b, int n) {
    int i = blockIdx.x * 256 + threadIdx.x;
    if (i < n) b[i] = a[i];
}

// counting-sort by (dst,rel): srcidx[pos] = src
__global__ __launch_bounds__(256) void fill_kernel(const int* __restrict__ src,
                                                   const int* __restrict__ dst,
                                                   const int* __restrict__ typ,
                                                   int* __restrict__ start,
                                                   int* __restrict__ srcidx, int E) {
    int e = blockIdx.x * 256 + threadIdx.x;
    if (e >= E) return;
    int pos = atomicAdd(&start[dst[e] * NR + typ[e]], 1);
    srcidx[pos] = src[e];
}

// ---------- weight pack: Bt[n][k] fp16, k = r*128+d for k<1024, else root[k-1024] ----------
__global__ __launch_bounds__(256) void pack_b_kernel(const float* __restrict__ W,
                                                     const float* __restrict__ root,
                                                     unsigned short* __restrict__ Bt, int N) {
    int i = blockIdx.x * 256 + threadIdx.x;
    if (i >= N * KT) return;
    int k = i % KT, n = i / KT;
    float v = (k < 1024) ? W[(size_t)k * N + n] : root[(size_t)(k - 1024) * N + n];
    Bt[(size_t)n * KT + k] = f2h(v);
}

// ---------- aggregation: one wave per dst; Abig[dst] = [mean_r(x[src]) for r | x[dst]] fp16 ----------
__global__ __launch_bounds__(256) void agg1_kernel(const int* __restrict__ rp,
                                                   const int* __restrict__ srcidx,
                                                   const float* __restrict__ inv,
                                                   const float* __restrict__ x,
                                                   unsigned short* __restrict__ A) {
    int w = (blockIdx.x * 256 + threadIdx.x) >> 6;
    int lane = threadIdx.x & 63;
    if (w >= NN) return;
    unsigned short* arow = A + (size_t)w * KT;
    const float2* x2 = (const float2*)x;
#pragma unroll 1
    for (int r = 0; r < NR; ++r) {
        int beg = rp[w * NR + r], end = rp[w * NR + r + 1];
        float sc = inv[w * NR + r];
        float ax = 0.f, ay = 0.f;
        for (int i = beg; i < end; ++i) {
            float2 v = x2[(size_t)srcidx[i] * 64 + lane];
            ax += v.x; ay += v.y;
        }
        arow[r * 128 + lane * 2]     = f2h(ax * sc);
        arow[r * 128 + lane * 2 + 1] = f2h(ay * sc);
    }
    float2 v = x2[(size_t)w * 64 + lane];
    arow[1024 + lane * 2]     = f2h(v.x);
    arow[1024 + lane * 2 + 1] = f2h(v.y);
}

// same but input is fp16 h1
__global__ __launch_bounds__(256) void agg2_kernel(const int* __restrict__ rp,
                                                   const int* __restrict__ srcidx,
                                                   const float* __restrict__ inv,
                                                   const unsigned short* __restrict__ h,
                                                   unsigned short* __restrict__ A) {
    int w = (blockIdx.x * 256 + threadIdx.x) >> 6;
    int lane = threadIdx.x & 63;
    if (w >= NN) return;
    unsigned short* arow = A + (size_t)w * KT;
    const unsigned int* h2 = (const unsigned int*)h;
#pragma unroll 1
    for (int r = 0; r < NR; ++r) {
        int beg = rp[w * NR + r], end = rp[w * NR + r + 1];
        float sc = inv[w * NR + r];
        float ax = 0.f, ay = 0.f;
        for (int i = beg; i < end; ++i) {
            unsigned int p = h2[(size_t)srcidx[i] * 64 + lane];
            ax += h2f((unsigned short)(p & 0xFFFFu));
            ay += h2f((unsigned short)(p >> 16));
        }
        arow[r * 128 + lane * 2]     = f2h(ax * sc);
        arow[r * 128 + lane * 2 + 1] = f2h(ay * sc);
    }
    ((unsigned int*)(arow + 1024))[lane] = h2[(size_t)w * 64 + lane];  // copy fp16 pair
}

// ---------- fp16 MFMA GEMM: C[M,NT] = A[M,KT] @ Bt^T + bias; 64xNT tile, BK=64 ----------
// FINAL: fp32 out with sigmoid (ld=NT); else fp16 out (ld=NT).
template <int NT, bool FINAL>
__global__ __launch_bounds__(256) void gemm_f16(const unsigned short* __restrict__ A,
                                                const unsigned short* __restrict__ Bt,
                                                const float* __restrict__ bias,
                                                void* __restrict__ Cout) {
    __shared__ __align__(16) unsigned short As[64 * 64];
    __shared__ __align__(16) unsigned short Bs[NT * 64];
    const int t = threadIdx.x;
    const int w = t >> 6, lane = t & 63;
    const int q = lane >> 4, m = lane & 15;
    const int wr = w >> 1, wc = w & 1;     // 2x2 wave grid: rows wr*32, cols wc*(NT/2)
    const int bm = blockIdx.x * 64;
    constexpr int WNB = NT / 32;           // 16-col frags per wave

    f32x4 acc[2][WNB];
#pragma unroll
    for (int mb = 0; mb < 2; ++mb)
#pragma unroll
        for (int nb = 0; nb < WNB; ++nb) acc[mb][nb] = (f32x4)0.f;

    const int srow = lane >> 3, schk = lane & 7;   // staging: lane -> (row-in-8, 16B chunk)

    for (int k0 = 0; k0 < KT; k0 += 64) {
        // A tile: 64 rows x 64 fp16 (8 KB) = 8 wave-loads of 1 KB
#pragma unroll
        for (int ii = 0; ii < 2; ++ii) {
            int i = w * 2 + ii;
            int grow = bm + i * 8 + srow;
            if (grow >= NN) grow = NN - 1;
            const unsigned short* g = A + (size_t)grow * KT + k0 + schk * 8;
            __builtin_amdgcn_global_load_lds((gvoid_t*)g, (svoid_t*)(As + i * 512), 16, 0, 0);
        }
        // B tile: NT rows x 64 fp16 = NT/8 wave-loads
#pragma unroll
        for (int ii = 0; ii < NT / 32; ++ii) {
            int i = w * (NT / 32) + ii;
            int row = i * 8 + srow;
            const unsigned short* g = Bt + (size_t)row * KT + k0 + schk * 8;
            __builtin_amdgcn_global_load_lds((gvoid_t*)g, (svoid_t*)(Bs + i * 512), 16, 0, 0);
        }
        __syncthreads();
#pragma unroll
        for (int s = 0; s < 2; ++s) {
            half8 af[2], bf[WNB];
#pragma unroll
            for (int mb = 0; mb < 2; ++mb)
                af[mb] = __builtin_bit_cast(half8,
                    *(const short8*)(As + (wr * 32 + mb * 16 + m) * 64 + s * 32 + q * 8));
#pragma unroll
            for (int nb = 0; nb < WNB; ++nb)
                bf[nb] = __builtin_bit_cast(half8,
                    *(const short8*)(Bs + (wc * (NT / 2) + nb * 16 + m) * 64 + s * 32 + q * 8));
#pragma unroll
            for (int mb = 0; mb < 2; ++mb)
#pragma unroll
                for (int nb = 0; nb < WNB; ++nb)
                    acc[mb][nb] = __builtin_amdgcn_mfma_f32_16x16x32_f16(af[mb], bf[nb],
                                                                         acc[mb][nb], 0, 0, 0);
        }
        __syncthreads();
    }

    // epilogue: C/D layout col=lane&15, row=quad*4+reg
#pragma unroll
    for (int mb = 0; mb < 2; ++mb)
#pragma unroll
        for (int nb = 0; nb < WNB; ++nb) {
            int col = wc * (NT / 2) + nb * 16 + m;
            float bv = bias[col];
#pragma unroll
            for (int j = 0; j < 4; ++j) {
                int grow = bm + wr * 32 + mb * 16 + q * 4 + j;
                if (grow < NN) {
                    float v = acc[mb][nb][j] + bv;
                    if (FINAL)
                        ((float*)Cout)[(size_t)grow * NT + col] = 1.f / (1.f + __expf(-v));
                    else
                        ((unsigned short*)Cout)[(size_t)grow * NT + col] = f2h(v);
                }
            }
        }
}

extern "C" void kernel_launch(void* const* d_in, const int* in_sizes, int n_in,
                              void* d_out, int out_size, void* d_ws, size_t ws_size,
                              hipStream_t stream) {
    const float* x     = (const float*)d_in[0];
    const int*   esrc  = (const int*)d_in[1];
    const int*   edst  = (const int*)d_in[2];
    const int*   etyp  = (const int*)d_in[3];
    const float* W1    = (const float*)d_in[4];
    const float* root1 = (const float*)d_in[5];
    const float* b1    = (const float*)d_in[6];
    const float* W2    = (const float*)d_in[7];
    const float* root2 = (const float*)d_in[8];
    const float* b2    = (const float*)d_in[9];
    float* out = (float*)d_out;

    char* ws = (char*)d_ws;
    unsigned short* Bt1    = (unsigned short*)ws; ws += (size_t)128 * KT * 2;  // 288 KB
    unsigned short* Bt2    = (unsigned short*)ws; ws += (size_t)64 * KT * 2;   // 144 KB
    int*            cnt    = (int*)ws;            ws += (size_t)NN * NR * 4;   // 1.6 MB
    float*          inv    = (float*)ws;          ws += (size_t)NN * NR * 4;   // 1.6 MB
    int*            rp     = (int*)ws;            ws += (size_t)(NN * NR + 64) * 4;
    int*            start  = (int*)ws;            ws += (size_t)NN * NR * 4;   // 1.6 MB
    int*            srcidx = (int*)ws;            ws += (size_t)NE * 4;        // 2.56 MB
    unsigned short* h1b    = (unsigned short*)ws; ws += (size_t)NN * 128 * 2;  // 12.8 MB
    unsigned short* Abig   = (unsigned short*)ws;                              // 115.2 MB (shared)

    // CSR by (dst, rel)
    hipMemsetAsync(cnt, 0, (size_t)NN * NR * 4, stream);
    count_kernel<<<(NE + 255) / 256, 256, 0, stream>>>(edst, etyp, cnt, NE);
    inv_kernel<<<(NN * NR + 255) / 256, 256, 0, stream>>>(cnt, inv, NN * NR);
    scan_kernel<<<1, 1024, 0, stream>>>(cnt, rp, NN * NR);
    copy_kernel<<<(NN * NR + 255) / 256, 256, 0, stream>>>(rp, start, NN * NR);
    fill_kernel<<<(NE + 255) / 256, 256, 0, stream>>>(esrc, edst, etyp, start, srcidx, NE);

    // weight packs (fp16)
    pack_b_kernel<<<(128 * KT + 255) / 256, 256, 0, stream>>>(W1, root1, Bt1, 128);
    pack_b_kernel<<<(64 * KT + 255) / 256, 256, 0, stream>>>(W2, root2, Bt2, 64);

    const int agrid = (NN * 64 + 255) / 256;   // one wave per dst
    const int ggrid = (NN + 63) / 64;          // 64-row GEMM tiles

    // layer 1: aggregate x -> Abig, GEMM -> h1b (fp16)
    agg1_kernel<<<agrid, 256, 0, stream>>>(rp, srcidx, inv, x, Abig);
    gemm_f16<128, false><<<ggrid, 256, 0, stream>>>(Abig, Bt1, b1, h1b);

    // layer 2: aggregate h1b -> Abig, GEMM (+bias+sigmoid) -> out
    agg2_kernel<<<agrid, 256, 0, stream>>>(rp, srcidx, inv, h1b, Abig);
    gemm_f16<64, true><<<ggrid, 256, 0, stream>>>(Abig, Bt2, b2, out);
}

// Round 5
// 416.600 us; speedup vs baseline: 2.4898x; 2.4898x over previous
//
#include <hip/hip_runtime.h>
#include <math.h>

#define NN 50000
#define NE 640000
#define NR 8
#define KT 1152           // 8*128 (relations) + 128 (root)
#define SCAN_N (NN * NR)  // 400000 segments
#define SCAN_CH 2048      // elements per scan block
#define SCAN_NB ((SCAN_N + SCAN_CH - 1) / SCAN_CH)  // 196

typedef __attribute__((ext_vector_type(8))) _Float16 half8;
typedef __attribute__((ext_vector_type(8))) short short8;
typedef __attribute__((ext_vector_type(4))) float f32x4;
typedef const void __attribute__((address_space(1))) gvoid_t;
typedef void __attribute__((address_space(3))) svoid_t;

__device__ __forceinline__ unsigned short f2h(float f) {
    _Float16 h = (_Float16)f;                       // v_cvt_f16_f32, RNE
    return __builtin_bit_cast(unsigned short, h);
}
__device__ __forceinline__ float h2f(unsigned short u) {
    return (float)__builtin_bit_cast(_Float16, u);
}

// ---------- preprocessing ----------
__global__ __launch_bounds__(256) void count_kernel(const int* __restrict__ dst,
                                                    const int* __restrict__ typ,
                                                    int* __restrict__ cnt, int E) {
    int e = blockIdx.x * 256 + threadIdx.x;
    if (e < E) atomicAdd(&cnt[dst[e] * NR + typ[e]], 1);
}

__global__ __launch_bounds__(256) void inv_kernel(const int* __restrict__ cnt,
                                                  float* __restrict__ inv, int n) {
    int i = blockIdx.x * 256 + threadIdx.x;
    if (i < n) {
        int c = cnt[i];
        inv[i] = 1.0f / (float)(c > 1 ? c : 1);
    }
}

// ---- hierarchical scan: (1) per-block local exclusive prefix + block sums
__global__ __launch_bounds__(256) void scan1_kernel(const int* __restrict__ cnt,
                                                    int* __restrict__ loc,
                                                    int* __restrict__ bsum) {
    __shared__ int s[256];
    const int t = threadIdx.x;
    const int base = blockIdx.x * SCAN_CH + t * 8;
    int v[8];
    int sum = 0;
#pragma unroll
    for (int j = 0; j < 8; ++j) {
        int idx = base + j;
        v[j] = (idx < SCAN_N) ? cnt[idx] : 0;
        sum += v[j];
    }
    s[t] = sum;
    __syncthreads();
    for (int off = 1; off < 256; off <<= 1) {
        int u = (t >= off) ? s[t - off] : 0;
        __syncthreads();
        s[t] += u;
        __syncthreads();
    }
    int run = (t == 0) ? 0 : s[t - 1];
#pragma unroll
    for (int j = 0; j < 8; ++j) {
        int idx = base + j;
        if (idx < SCAN_N) loc[idx] = run;
        run += v[j];
    }
    if (t == 255) bsum[blockIdx.x] = s[255];
}

// ---- (2) scan the block sums (nb <= 256)
__global__ __launch_bounds__(256) void scan2_kernel(const int* __restrict__ bsum,
                                                    int* __restrict__ boff, int nb) {
    __shared__ int s[256];
    const int t = threadIdx.x;
    s[t] = (t < nb) ? bsum[t] : 0;
    __syncthreads();
    for (int off = 1; off < 256; off <<= 1) {
        int u = (t >= off) ? s[t - off] : 0;
        __syncthreads();
        s[t] += u;
        __syncthreads();
    }
    if (t < nb) boff[t] = (t == 0) ? 0 : s[t - 1];
    if (t == nb - 1) boff[nb] = s[t];
}

// ---- (3) add block offsets in place; also produce the mutable `start` copy
__global__ __launch_bounds__(256) void scan3_kernel(int* __restrict__ rowptr,
                                                    int* __restrict__ start,
                                                    const int* __restrict__ boff, int nb) {
    const int b = blockIdx.x, t = threadIdx.x;
    const int add = boff[b];
#pragma unroll
    for (int j = 0; j < 8; ++j) {
        int idx = b * SCAN_CH + t * 8 + j;
        if (idx < SCAN_N) {
            int v = rowptr[idx] + add;
            rowptr[idx] = v;
            start[idx] = v;
        }
    }
    if (b == 0 && t == 0) rowptr[SCAN_N] = boff[nb];
}

// counting-sort by (dst,rel): srcidx[pos] = src
__global__ __launch_bounds__(256) void fill_kernel(const int* __restrict__ src,
                                                   const int* __restrict__ dst,
                                                   const int* __restrict__ typ,
                                                   int* __restrict__ start,
                                                   int* __restrict__ srcidx, int E) {
    int e = blockIdx.x * 256 + threadIdx.x;
    if (e >= E) return;
    int pos = atomicAdd(&start[dst[e] * NR + typ[e]], 1);
    srcidx[pos] = src[e];
}

// ---------- weight pack: Bt[n][k] fp16, k = r*128+d for k<1024, else root[k-1024] ----------
__global__ __launch_bounds__(256) void pack_b_kernel(const float* __restrict__ W,
                                                     const float* __restrict__ root,
                                                     unsigned short* __restrict__ Bt, int N) {
    int i = blockIdx.x * 256 + threadIdx.x;
    if (i >= N * KT) return;
    int k = i % KT, n = i / KT;
    float v = (k < 1024) ? W[(size_t)k * N + n] : root[(size_t)(k - 1024) * N + n];
    Bt[(size_t)n * KT + k] = f2h(v);
}

// ---------- aggregation: one wave per dst; Abig[dst] = [mean_r(x[src]) for r | x[dst]] fp16 ----------
__global__ __launch_bounds__(256) void agg1_kernel(const int* __restrict__ rp,
                                                   const int* __restrict__ srcidx,
                                                   const float* __restrict__ inv,
                                                   const float* __restrict__ x,
                                                   unsigned short* __restrict__ A) {
    int w = (blockIdx.x * 256 + threadIdx.x) >> 6;
    int lane = threadIdx.x & 63;
    if (w >= NN) return;
    unsigned short* arow = A + (size_t)w * KT;
    const float2* x2 = (const float2*)x;
#pragma unroll 1
    for (int r = 0; r < NR; ++r) {
        int beg = rp[w * NR + r], end = rp[w * NR + r + 1];
        float sc = inv[w * NR + r];
        float ax = 0.f, ay = 0.f;
        for (int i = beg; i < end; ++i) {
            float2 v = x2[(size_t)srcidx[i] * 64 + lane];
            ax += v.x; ay += v.y;
        }
        arow[r * 128 + lane * 2]     = f2h(ax * sc);
        arow[r * 128 + lane * 2 + 1] = f2h(ay * sc);
    }
    float2 v = x2[(size_t)w * 64 + lane];
    arow[1024 + lane * 2]     = f2h(v.x);
    arow[1024 + lane * 2 + 1] = f2h(v.y);
}

// same but input is fp16 h1
__global__ __launch_bounds__(256) void agg2_kernel(const int* __restrict__ rp,
                                                   const int* __restrict__ srcidx,
                                                   const float* __restrict__ inv,
                                                   const unsigned short* __restrict__ h,
                                                   unsigned short* __restrict__ A) {
    int w = (blockIdx.x * 256 + threadIdx.x) >> 6;
    int lane = threadIdx.x & 63;
    if (w >= NN) return;
    unsigned short* arow = A + (size_t)w * KT;
    const unsigned int* h2 = (const unsigned int*)h;
#pragma unroll 1
    for (int r = 0; r < NR; ++r) {
        int beg = rp[w * NR + r], end = rp[w * NR + r + 1];
        float sc = inv[w * NR + r];
        float ax = 0.f, ay = 0.f;
        for (int i = beg; i < end; ++i) {
            unsigned int p = h2[(size_t)srcidx[i] * 64 + lane];
            ax += h2f((unsigned short)(p & 0xFFFFu));
            ay += h2f((unsigned short)(p >> 16));
        }
        arow[r * 128 + lane * 2]     = f2h(ax * sc);
        arow[r * 128 + lane * 2 + 1] = f2h(ay * sc);
    }
    ((unsigned int*)(arow + 1024))[lane] = h2[(size_t)w * 64 + lane];  // copy fp16 pair
}

// ---------- fp16 MFMA GEMM: C[M,NT] = A[M,KT] @ Bt^T + bias; 64xNT tile, BK=64 ----------
// FINAL: fp32 out with sigmoid (ld=NT); else fp16 out (ld=NT).
template <int NT, bool FINAL>
__global__ __launch_bounds__(256) void gemm_f16(const unsigned short* __restrict__ A,
                                                const unsigned short* __restrict__ Bt,
                                                const float* __restrict__ bias,
                                                void* __restrict__ Cout) {
    __shared__ __align__(16) unsigned short As[64 * 64];
    __shared__ __align__(16) unsigned short Bs[NT * 64];
    const int t = threadIdx.x;
    const int w = t >> 6, lane = t & 63;
    const int q = lane >> 4, m = lane & 15;
    const int wr = w >> 1, wc = w & 1;     // 2x2 wave grid: rows wr*32, cols wc*(NT/2)
    const int bm = blockIdx.x * 64;
    constexpr int WNB = NT / 32;           // 16-col frags per wave

    f32x4 acc[2][WNB];
#pragma unroll
    for (int mb = 0; mb < 2; ++mb)
#pragma unroll
        for (int nb = 0; nb < WNB; ++nb) acc[mb][nb] = (f32x4)0.f;

    const int srow = lane >> 3, schk = lane & 7;   // staging: lane -> (row-in-8, 16B chunk)

    for (int k0 = 0; k0 < KT; k0 += 64) {
        // A tile: 64 rows x 64 fp16 (8 KB) = 8 wave-loads of 1 KB
#pragma unroll
        for (int ii = 0; ii < 2; ++ii) {
            int i = w * 2 + ii;
            int grow = bm + i * 8 + srow;
            if (grow >= NN) grow = NN - 1;
            const unsigned short* g = A + (size_t)grow * KT + k0 + schk * 8;
            __builtin_amdgcn_global_load_lds((gvoid_t*)g, (svoid_t*)(As + i * 512), 16, 0, 0);
        }
        // B tile: NT rows x 64 fp16 = NT/8 wave-loads
#pragma unroll
        for (int ii = 0; ii < NT / 32; ++ii) {
            int i = w * (NT / 32) + ii;
            int row = i * 8 + srow;
            const unsigned short* g = Bt + (size_t)row * KT + k0 + schk * 8;
            __builtin_amdgcn_global_load_lds((gvoid_t*)g, (svoid_t*)(Bs + i * 512), 16, 0, 0);
        }
        __syncthreads();
#pragma unroll
        for (int s = 0; s < 2; ++s) {
            half8 af[2], bf[WNB];
#pragma unroll
            for (int mb = 0; mb < 2; ++mb)
                af[mb] = __builtin_bit_cast(half8,
                    *(const short8*)(As + (wr * 32 + mb * 16 + m) * 64 + s * 32 + q * 8));
#pragma unroll
            for (int nb = 0; nb < WNB; ++nb)
                bf[nb] = __builtin_bit_cast(half8,
                    *(const short8*)(Bs + (wc * (NT / 2) + nb * 16 + m) * 64 + s * 32 + q * 8));
#pragma unroll
            for (int mb = 0; mb < 2; ++mb)
#pragma unroll
                for (int nb = 0; nb < WNB; ++nb)
                    acc[mb][nb] = __builtin_amdgcn_mfma_f32_16x16x32_f16(af[mb], bf[nb],
                                                                         acc[mb][nb], 0, 0, 0);
        }
        __syncthreads();
    }

    // epilogue: C/D layout col=lane&15, row=quad*4+reg
#pragma unroll
    for (int mb = 0; mb < 2; ++mb)
#pragma unroll
        for (int nb = 0; nb < WNB; ++nb) {
            int col = wc * (NT / 2) + nb * 16 + m;
            float bv = bias[col];
#pragma unroll
            for (int j = 0; j < 4; ++j) {
                int grow = bm + wr * 32 + mb * 16 + q * 4 + j;
                if (grow < NN) {
                    float v = acc[mb][nb][j] + bv;
                    if (FINAL)
                        ((float*)Cout)[(size_t)grow * NT + col] = 1.f / (1.f + __expf(-v));
                    else
                        ((unsigned short*)Cout)[(size_t)grow * NT + col] = f2h(v);
                }
            }
        }
}

extern "C" void kernel_launch(void* const* d_in, const int* in_sizes, int n_in,
                              void* d_out, int out_size, void* d_ws, size_t ws_size,
                              hipStream_t stream) {
    const float* x     = (const float*)d_in[0];
    const int*   esrc  = (const int*)d_in[1];
    const int*   edst  = (const int*)d_in[2];
    const int*   etyp  = (const int*)d_in[3];
    const float* W1    = (const float*)d_in[4];
    const float* root1 = (const float*)d_in[5];
    const float* b1    = (const float*)d_in[6];
    const float* W2    = (const float*)d_in[7];
    const float* root2 = (const float*)d_in[8];
    const float* b2    = (const float*)d_in[9];
    float* out = (float*)d_out;

    char* ws = (char*)d_ws;
    unsigned short* Bt1    = (unsigned short*)ws; ws += (size_t)128 * KT * 2;  // 288 KB
    unsigned short* Bt2    = (unsigned short*)ws; ws += (size_t)64 * KT * 2;   // 144 KB
    int*            cnt    = (int*)ws;            ws += (size_t)SCAN_N * 4;    // 1.6 MB
    float*          inv    = (float*)ws;          ws += (size_t)SCAN_N * 4;    // 1.6 MB
    int*            rp     = (int*)ws;            ws += (size_t)(SCAN_N + 64) * 4;
    int*            start  = (int*)ws;            ws += (size_t)SCAN_N * 4;    // 1.6 MB
    int*            bsum   = (int*)ws;            ws += (size_t)256 * 4;
    int*            boff   = (int*)ws;            ws += (size_t)257 * 4;
    int*            srcidx = (int*)ws;            ws += (size_t)NE * 4;        // 2.56 MB
    unsigned short* h1b    = (unsigned short*)ws; ws += (size_t)NN * 128 * 2;  // 12.8 MB
    unsigned short* Abig   = (unsigned short*)ws;                              // 115.2 MB (shared)

    // CSR by (dst, rel) — hierarchical scan, fully parallel
    hipMemsetAsync(cnt, 0, (size_t)SCAN_N * 4, stream);
    count_kernel<<<(NE + 255) / 256, 256, 0, stream>>>(edst, etyp, cnt, NE);
    inv_kernel<<<(SCAN_N + 255) / 256, 256, 0, stream>>>(cnt, inv, SCAN_N);
    scan1_kernel<<<SCAN_NB, 256, 0, stream>>>(cnt, rp, bsum);
    scan2_kernel<<<1, 256, 0, stream>>>(bsum, boff, SCAN_NB);
    scan3_kernel<<<SCAN_NB, 256, 0, stream>>>(rp, start, boff, SCAN_NB);
    fill_kernel<<<(NE + 255) / 256, 256, 0, stream>>>(esrc, edst, etyp, start, srcidx, NE);

    // weight packs (fp16)
    pack_b_kernel<<<(128 * KT + 255) / 256, 256, 0, stream>>>(W1, root1, Bt1, 128);
    pack_b_kernel<<<(64 * KT + 255) / 256, 256, 0, stream>>>(W2, root2, Bt2, 64);

    const int agrid = (NN * 64 + 255) / 256;   // one wave per dst
    const int ggrid = (NN + 63) / 64;          // 64-row GEMM tiles

    // layer 1: aggregate x -> Abig, GEMM -> h1b (fp16)
    agg1_kernel<<<agrid, 256, 0, stream>>>(rp, srcidx, inv, x, Abig);
    gemm_f16<128, false><<<ggrid, 256, 0, stream>>>(Abig, Bt1, b1, h1b);

    // layer 2: aggregate h1b -> Abig, GEMM (+bias+sigmoid) -> out
    agg2_kernel<<<agrid, 256, 0, stream>>>(rp, srcidx, inv, h1b, Abig);
    gemm_f16<64, true><<<ggrid, 256, 0, stream>>>(Abig, Bt2, b2, out);
}

// Round 6
// 348.937 us; speedup vs baseline: 2.9726x; 1.1939x over previous
//
#include <hip/hip_runtime.h>
#include <math.h>

#define NN 50000
#define NE 640000
#define NR 8
#define KT 1152           // 8*128 (relations) + 128 (root)
#define KA 1024           // Abig row length (root bypassed)
#define SCAN_N (NN * NR)  // 400000 segments
#define SCAN_CH 2048      // elements per scan block
#define SCAN_NB ((SCAN_N + SCAN_CH - 1) / SCAN_CH)  // 196

typedef __attribute__((ext_vector_type(8))) _Float16 half8;
typedef __attribute__((ext_vector_type(8))) short short8;
typedef __attribute__((ext_vector_type(4))) float f32x4;
typedef const void __attribute__((address_space(1))) gvoid_t;
typedef void __attribute__((address_space(3))) svoid_t;

__device__ __forceinline__ unsigned short f2h(float f) {
    _Float16 h = (_Float16)f;                       // v_cvt_f16_f32, RNE
    return __builtin_bit_cast(unsigned short, h);
}
__device__ __forceinline__ float h2f(unsigned short u) {
    return (float)__builtin_bit_cast(_Float16, u);
}

// ---------- preprocessing ----------
__global__ __launch_bounds__(256) void count_kernel(const int* __restrict__ dst,
                                                    const int* __restrict__ typ,
                                                    int* __restrict__ cnt, int E) {
    int e = blockIdx.x * 256 + threadIdx.x;
    if (e < E) atomicAdd(&cnt[dst[e] * NR + typ[e]], 1);
}

__global__ __launch_bounds__(256) void inv_kernel(const int* __restrict__ cnt,
                                                  float* __restrict__ inv, int n) {
    int i = blockIdx.x * 256 + threadIdx.x;
    if (i < n) {
        int c = cnt[i];
        inv[i] = 1.0f / (float)(c > 1 ? c : 1);
    }
}

// ---- hierarchical scan
__global__ __launch_bounds__(256) void scan1_kernel(const int* __restrict__ cnt,
                                                    int* __restrict__ loc,
                                                    int* __restrict__ bsum) {
    __shared__ int s[256];
    const int t = threadIdx.x;
    const int base = blockIdx.x * SCAN_CH + t * 8;
    int v[8];
    int sum = 0;
#pragma unroll
    for (int j = 0; j < 8; ++j) {
        int idx = base + j;
        v[j] = (idx < SCAN_N) ? cnt[idx] : 0;
        sum += v[j];
    }
    s[t] = sum;
    __syncthreads();
    for (int off = 1; off < 256; off <<= 1) {
        int u = (t >= off) ? s[t - off] : 0;
        __syncthreads();
        s[t] += u;
        __syncthreads();
    }
    int run = (t == 0) ? 0 : s[t - 1];
#pragma unroll
    for (int j = 0; j < 8; ++j) {
        int idx = base + j;
        if (idx < SCAN_N) loc[idx] = run;
        run += v[j];
    }
    if (t == 255) bsum[blockIdx.x] = s[255];
}

__global__ __launch_bounds__(256) void scan2_kernel(const int* __restrict__ bsum,
                                                    int* __restrict__ boff, int nb) {
    __shared__ int s[256];
    const int t = threadIdx.x;
    s[t] = (t < nb) ? bsum[t] : 0;
    __syncthreads();
    for (int off = 1; off < 256; off <<= 1) {
        int u = (t >= off) ? s[t - off] : 0;
        __syncthreads();
        s[t] += u;
        __syncthreads();
    }
    if (t < nb) boff[t] = (t == 0) ? 0 : s[t - 1];
    if (t == nb - 1) boff[nb] = s[t];
}

__global__ __launch_bounds__(256) void scan3_kernel(int* __restrict__ rowptr,
                                                    int* __restrict__ start,
                                                    const int* __restrict__ boff, int nb) {
    const int b = blockIdx.x, t = threadIdx.x;
    const int add = boff[b];
#pragma unroll
    for (int j = 0; j < 8; ++j) {
        int idx = b * SCAN_CH + t * 8 + j;
        if (idx < SCAN_N) {
            int v = rowptr[idx] + add;
            rowptr[idx] = v;
            start[idx] = v;
        }
    }
    if (b == 0 && t == 0) rowptr[SCAN_N] = boff[nb];
}

// counting-sort by (dst,rel): srcrel[pos] = src | rel<<20
__global__ __launch_bounds__(256) void fill_kernel(const int* __restrict__ src,
                                                   const int* __restrict__ dst,
                                                   const int* __restrict__ typ,
                                                   int* __restrict__ start,
                                                   int* __restrict__ srcrel, int E) {
    int e = blockIdx.x * 256 + threadIdx.x;
    if (e >= E) return;
    int r = typ[e];
    int pos = atomicAdd(&start[dst[e] * NR + r], 1);
    srcrel[pos] = src[e] | (r << 20);
}

// ---------- x (fp32, [NN,128]) -> xh (fp16) ----------
__global__ __launch_bounds__(256) void cvt_kernel(const float* __restrict__ x,
                                                  unsigned short* __restrict__ xh, int n4) {
    int i = blockIdx.x * 256 + threadIdx.x;
    if (i >= n4) return;
    float4 v = ((const float4*)x)[i];
    uint2 u;
    u.x = (unsigned)f2h(v.x) | ((unsigned)f2h(v.y) << 16);
    u.y = (unsigned)f2h(v.z) | ((unsigned)f2h(v.w) << 16);
    ((uint2*)xh)[i] = u;
}

// ---------- weight pack: Bt[n][k] fp16, k = r*128+d for k<1024, else root[k-1024] ----------
__global__ __launch_bounds__(256) void pack_b_kernel(const float* __restrict__ W,
                                                     const float* __restrict__ root,
                                                     unsigned short* __restrict__ Bt, int N) {
    int i = blockIdx.x * 256 + threadIdx.x;
    if (i >= N * KT) return;
    int k = i % KT, n = i / KT;
    float v = (k < 1024) ? W[(size_t)k * N + n] : root[(size_t)(k - 1024) * N + n];
    Bt[(size_t)n * KT + k] = f2h(v);
}

// ---------- aggregation: one wave per dst, flat edge loop, fp32 LDS accumulators ----------
// A[w][r*128+c] = inv[w*8+r] * sum_{e in seg(w,r)} X[src_e][c]   (fp16 out, [NN,KA])
__global__ __launch_bounds__(256) void agg_kernel(const int* __restrict__ rp,
                                                  const int* __restrict__ srcrel,
                                                  const float* __restrict__ inv,
                                                  const unsigned short* __restrict__ X,
                                                  unsigned short* __restrict__ A) {
    __shared__ float acc[4][NR][128];
    const int slot = threadIdx.x >> 6, lane = threadIdx.x & 63;
    const int w = blockIdx.x * 4 + slot;
    if (w >= NN) return;

#pragma unroll
    for (int r = 0; r < NR; ++r)
        *(float2*)&acc[slot][r][lane * 2] = make_float2(0.f, 0.f);

    const unsigned int* X2 = (const unsigned int*)X;   // half2 per lane
    const int beg = rp[w * NR], end = rp[w * NR + NR];

    int i = beg;
    const int n2 = beg + ((end - beg) & ~1);
    for (; i < n2; i += 2) {                           // 2x unroll: 2 gathers in flight
        int p0 = srcrel[i], p1 = srcrel[i + 1];
        unsigned h0 = X2[(size_t)(p0 & 0xFFFFF) * 64 + lane];
        unsigned h1 = X2[(size_t)(p1 & 0xFFFFF) * 64 + lane];
        {
            float2* a = (float2*)&acc[slot][((unsigned)p0) >> 20][lane * 2];
            float2 c = *a;
            c.x += h2f((unsigned short)(h0 & 0xFFFFu));
            c.y += h2f((unsigned short)(h0 >> 16));
            *a = c;
        }
        {
            float2* a = (float2*)&acc[slot][((unsigned)p1) >> 20][lane * 2];
            float2 c = *a;
            c.x += h2f((unsigned short)(h1 & 0xFFFFu));
            c.y += h2f((unsigned short)(h1 >> 16));
            *a = c;
        }
    }
    if (i < end) {
        int p0 = srcrel[i];
        unsigned h0 = X2[(size_t)(p0 & 0xFFFFF) * 64 + lane];
        float2* a = (float2*)&acc[slot][((unsigned)p0) >> 20][lane * 2];
        float2 c = *a;
        c.x += h2f((unsigned short)(h0 & 0xFFFFu));
        c.y += h2f((unsigned short)(h0 >> 16));
        *a = c;
    }

    unsigned int* Arow = (unsigned int*)(A + (size_t)w * KA);
#pragma unroll
    for (int r = 0; r < NR; ++r) {
        float sc = inv[w * NR + r];
        float2 v = *(float2*)&acc[slot][r][lane * 2];
        Arow[r * 64 + lane] = (unsigned)f2h(v.x * sc) | ((unsigned)f2h(v.y * sc) << 16);
    }
}

// ---------- fp16 MFMA GEMM: C[M,NT] = [A | Aroot][M,KT] @ Bt^T + bias ----------
// A is [M,KA] (relation means), Aroot is [M,128] (root features, read in place).
// FINAL: fp32 out with sigmoid; else fp16 out.
template <int NT, bool FINAL>
__global__ __launch_bounds__(256) void gemm_f16(const unsigned short* __restrict__ A,
                                                const unsigned short* __restrict__ Aroot,
                                                const unsigned short* __restrict__ Bt,
                                                const float* __restrict__ bias,
                                                void* __restrict__ Cout) {
    __shared__ __align__(16) unsigned short As[64 * 64];
    __shared__ __align__(16) unsigned short Bs[NT * 64];
    const int t = threadIdx.x;
    const int w = t >> 6, lane = t & 63;
    const int q = lane >> 4, m = lane & 15;
    const int wr = w >> 1, wc = w & 1;     // 2x2 wave grid: rows wr*32, cols wc*(NT/2)
    const int bm = blockIdx.x * 64;
    constexpr int WNB = NT / 32;           // 16-col frags per wave

    f32x4 acc[2][WNB];
#pragma unroll
    for (int mb = 0; mb < 2; ++mb)
#pragma unroll
        for (int nb = 0; nb < WNB; ++nb) acc[mb][nb] = (f32x4)0.f;

    const int srow = lane >> 3, schk = lane & 7;   // staging: lane -> (row-in-8, 16B chunk)

    for (int k0 = 0; k0 < KT; k0 += 64) {
        // A tile: 64 rows x 64 fp16 (8 KB); k>=1024 reads root features in place
#pragma unroll
        for (int ii = 0; ii < 2; ++ii) {
            int i = w * 2 + ii;
            int grow = bm + i * 8 + srow;
            if (grow >= NN) grow = NN - 1;
            const unsigned short* g =
                (k0 < KA) ? A + (size_t)grow * KA + k0 + schk * 8
                          : Aroot + (size_t)grow * 128 + (k0 - KA) + schk * 8;
            __builtin_amdgcn_global_load_lds((gvoid_t*)g, (svoid_t*)(As + i * 512), 16, 0, 0);
        }
        // B tile: NT rows x 64 fp16
#pragma unroll
        for (int ii = 0; ii < NT / 32; ++ii) {
            int i = w * (NT / 32) + ii;
            int row = i * 8 + srow;
            const unsigned short* g = Bt + (size_t)row * KT + k0 + schk * 8;
            __builtin_amdgcn_global_load_lds((gvoid_t*)g, (svoid_t*)(Bs + i * 512), 16, 0, 0);
        }
        __syncthreads();
#pragma unroll
        for (int s = 0; s < 2; ++s) {
            half8 af[2], bf[WNB];
#pragma unroll
            for (int mb = 0; mb < 2; ++mb)
                af[mb] = __builtin_bit_cast(half8,
                    *(const short8*)(As + (wr * 32 + mb * 16 + m) * 64 + s * 32 + q * 8));
#pragma unroll
            for (int nb = 0; nb < WNB; ++nb)
                bf[nb] = __builtin_bit_cast(half8,
                    *(const short8*)(Bs + (wc * (NT / 2) + nb * 16 + m) * 64 + s * 32 + q * 8));
#pragma unroll
            for (int mb = 0; mb < 2; ++mb)
#pragma unroll
                for (int nb = 0; nb < WNB; ++nb)
                    acc[mb][nb] = __builtin_amdgcn_mfma_f32_16x16x32_f16(af[mb], bf[nb],
                                                                         acc[mb][nb], 0, 0, 0);
        }
        __syncthreads();
    }

    // epilogue: C/D layout col=lane&15, row=quad*4+reg
#pragma unroll
    for (int mb = 0; mb < 2; ++mb)
#pragma unroll
        for (int nb = 0; nb < WNB; ++nb) {
            int col = wc * (NT / 2) + nb * 16 + m;
            float bv = bias[col];
#pragma unroll
            for (int j = 0; j < 4; ++j) {
                int grow = bm + wr * 32 + mb * 16 + q * 4 + j;
                if (grow < NN) {
                    float v = acc[mb][nb][j] + bv;
                    if (FINAL)
                        ((float*)Cout)[(size_t)grow * NT + col] = 1.f / (1.f + __expf(-v));
                    else
                        ((unsigned short*)Cout)[(size_t)grow * NT + col] = f2h(v);
                }
            }
        }
}

extern "C" void kernel_launch(void* const* d_in, const int* in_sizes, int n_in,
                              void* d_out, int out_size, void* d_ws, size_t ws_size,
                              hipStream_t stream) {
    const float* x     = (const float*)d_in[0];
    const int*   esrc  = (const int*)d_in[1];
    const int*   edst  = (const int*)d_in[2];
    const int*   etyp  = (const int*)d_in[3];
    const float* W1    = (const float*)d_in[4];
    const float* root1 = (const float*)d_in[5];
    const float* b1    = (const float*)d_in[6];
    const float* W2    = (const float*)d_in[7];
    const float* root2 = (const float*)d_in[8];
    const float* b2    = (const float*)d_in[9];
    float* out = (float*)d_out;

    char* ws = (char*)d_ws;
    unsigned short* Bt1    = (unsigned short*)ws; ws += (size_t)128 * KT * 2;  // 288 KB
    unsigned short* Bt2    = (unsigned short*)ws; ws += (size_t)64 * KT * 2;   // 144 KB
    int*            cnt    = (int*)ws;            ws += (size_t)SCAN_N * 4;    // 1.6 MB
    float*          inv    = (float*)ws;          ws += (size_t)SCAN_N * 4;    // 1.6 MB
    int*            rp     = (int*)ws;            ws += (size_t)(SCAN_N + 64) * 4;
    int*            start  = (int*)ws;            ws += (size_t)SCAN_N * 4;    // 1.6 MB
    int*            bsum   = (int*)ws;            ws += (size_t)256 * 4;
    int*            boff   = (int*)ws;            ws += (size_t)257 * 4;
    int*            srcrel = (int*)ws;            ws += (size_t)NE * 4;        // 2.56 MB
    unsigned short* xh     = (unsigned short*)ws; ws += (size_t)NN * 128 * 2;  // 12.8 MB
    unsigned short* h1b    = (unsigned short*)ws; ws += (size_t)NN * 128 * 2;  // 12.8 MB
    unsigned short* Abig   = (unsigned short*)ws;                              // 102.4 MB

    // CSR by (dst, rel) — hierarchical scan, fully parallel
    hipMemsetAsync(cnt, 0, (size_t)SCAN_N * 4, stream);
    count_kernel<<<(NE + 255) / 256, 256, 0, stream>>>(edst, etyp, cnt, NE);
    inv_kernel<<<(SCAN_N + 255) / 256, 256, 0, stream>>>(cnt, inv, SCAN_N);
    scan1_kernel<<<SCAN_NB, 256, 0, stream>>>(cnt, rp, bsum);
    scan2_kernel<<<1, 256, 0, stream>>>(bsum, boff, SCAN_NB);
    scan3_kernel<<<SCAN_NB, 256, 0, stream>>>(rp, start, boff, SCAN_NB);
    fill_kernel<<<(NE + 255) / 256, 256, 0, stream>>>(esrc, edst, etyp, start, srcrel, NE);

    // fp16 conversions / packs
    cvt_kernel<<<(NN * 32 + 255) / 256, 256, 0, stream>>>(x, xh, NN * 32);
    pack_b_kernel<<<(128 * KT + 255) / 256, 256, 0, stream>>>(W1, root1, Bt1, 128);
    pack_b_kernel<<<(64 * KT + 255) / 256, 256, 0, stream>>>(W2, root2, Bt2, 64);

    const int agrid = (NN + 3) / 4;            // one wave per dst, 4 waves/block
    const int ggrid = (NN + 63) / 64;          // 64-row GEMM tiles

    // layer 1: aggregate xh -> Abig, GEMM (+root from xh) -> h1b (fp16)
    agg_kernel<<<agrid, 256, 0, stream>>>(rp, srcrel, inv, xh, Abig);
    gemm_f16<128, false><<<ggrid, 256, 0, stream>>>(Abig, xh, Bt1, b1, h1b);

    // layer 2: aggregate h1b -> Abig, GEMM (+root from h1b, +bias+sigmoid) -> out
    agg_kernel<<<agrid, 256, 0, stream>>>(rp, srcrel, inv, h1b, Abig);
    gemm_f16<64, true><<<ggrid, 256, 0, stream>>>(Abig, h1b, Bt2, b2, out);
}

// Round 7
// 329.999 us; speedup vs baseline: 3.1432x; 1.0574x over previous
//
#include <hip/hip_runtime.h>
#include <math.h>

#define NN 50000
#define NE 640000
#define NR 8
#define SCAN_N (NN * NR)  // 400000 segments
#define SCAN_CH 2048      // elements per scan block
#define SCAN_NB ((SCAN_N + SCAN_CH - 1) / SCAN_CH)  // 196

typedef __attribute__((ext_vector_type(8))) _Float16 half8;
typedef __attribute__((ext_vector_type(8))) short short8;
typedef __attribute__((ext_vector_type(4))) float f32x4;
typedef const void __attribute__((address_space(1))) gvoid_t;
typedef void __attribute__((address_space(3))) svoid_t;

__device__ __forceinline__ unsigned short f2h(float f) {
    _Float16 h = (_Float16)f;                       // v_cvt_f16_f32, RNE
    return __builtin_bit_cast(unsigned short, h);
}
__device__ __forceinline__ float h2f(unsigned short u) {
    return (float)__builtin_bit_cast(_Float16, u);
}

// ---------- preprocessing ----------
__global__ __launch_bounds__(256) void count_kernel(const int* __restrict__ dst,
                                                    const int* __restrict__ typ,
                                                    int* __restrict__ cnt, int E) {
    int e = blockIdx.x * 256 + threadIdx.x;
    if (e < E) atomicAdd(&cnt[dst[e] * NR + typ[e]], 1);
}

__global__ __launch_bounds__(256) void inv_kernel(const int* __restrict__ cnt,
                                                  float* __restrict__ inv, int n) {
    int i = blockIdx.x * 256 + threadIdx.x;
    if (i < n) {
        int c = cnt[i];
        inv[i] = 1.0f / (float)(c > 1 ? c : 1);
    }
}

// ---- hierarchical scan
__global__ __launch_bounds__(256) void scan1_kernel(const int* __restrict__ cnt,
                                                    int* __restrict__ loc,
                                                    int* __restrict__ bsum) {
    __shared__ int s[256];
    const int t = threadIdx.x;
    const int base = blockIdx.x * SCAN_CH + t * 8;
    int v[8];
    int sum = 0;
#pragma unroll
    for (int j = 0; j < 8; ++j) {
        int idx = base + j;
        v[j] = (idx < SCAN_N) ? cnt[idx] : 0;
        sum += v[j];
    }
    s[t] = sum;
    __syncthreads();
    for (int off = 1; off < 256; off <<= 1) {
        int u = (t >= off) ? s[t - off] : 0;
        __syncthreads();
        s[t] += u;
        __syncthreads();
    }
    int run = (t == 0) ? 0 : s[t - 1];
#pragma unroll
    for (int j = 0; j < 8; ++j) {
        int idx = base + j;
        if (idx < SCAN_N) loc[idx] = run;
        run += v[j];
    }
    if (t == 255) bsum[blockIdx.x] = s[255];
}

__global__ __launch_bounds__(256) void scan2_kernel(const int* __restrict__ bsum,
                                                    int* __restrict__ boff, int nb) {
    __shared__ int s[256];
    const int t = threadIdx.x;
    s[t] = (t < nb) ? bsum[t] : 0;
    __syncthreads();
    for (int off = 1; off < 256; off <<= 1) {
        int u = (t >= off) ? s[t - off] : 0;
        __syncthreads();
        s[t] += u;
        __syncthreads();
    }
    if (t < nb) boff[t] = (t == 0) ? 0 : s[t - 1];
    if (t == nb - 1) boff[nb] = s[t];
}

__global__ __launch_bounds__(256) void scan3_kernel(int* __restrict__ rowptr,
                                                    int* __restrict__ start,
                                                    const int* __restrict__ boff, int nb) {
    const int b = blockIdx.x, t = threadIdx.x;
    const int add = boff[b];
#pragma unroll
    for (int j = 0; j < 8; ++j) {
        int idx = b * SCAN_CH + t * 8 + j;
        if (idx < SCAN_N) {
            int v = rowptr[idx] + add;
            rowptr[idx] = v;
            start[idx] = v;
        }
    }
    if (b == 0 && t == 0) rowptr[SCAN_N] = boff[nb];
}

// counting-sort by (dst,rel): srcrel[pos] = src | rel<<20
__global__ __launch_bounds__(256) void fill_kernel(const int* __restrict__ src,
                                                   const int* __restrict__ dst,
                                                   const int* __restrict__ typ,
                                                   int* __restrict__ start,
                                                   int* __restrict__ srcrel, int E) {
    int e = blockIdx.x * 256 + threadIdx.x;
    if (e >= E) return;
    int r = typ[e];
    int pos = atomicAdd(&start[dst[e] * NR + r], 1);
    srcrel[pos] = src[e] | (r << 20);
}

// ---------- x (fp32, [NN,128]) -> xh (fp16) ----------
__global__ __launch_bounds__(256) void cvt_kernel(const float* __restrict__ x,
                                                  unsigned short* __restrict__ xh, int n4) {
    int i = blockIdx.x * 256 + threadIdx.x;
    if (i >= n4) return;
    float4 v = ((const float4*)x)[i];
    uint2 u;
    u.x = (unsigned)f2h(v.x) | ((unsigned)f2h(v.y) << 16);
    u.y = (unsigned)f2h(v.z) | ((unsigned)f2h(v.w) << 16);
    ((uint2*)xh)[i] = u;
}

// ---------- weight pack: Bt[n][k] fp16, n in [0,9*O): n<8*O -> W[r=n/O][k][o=n%O], else root[k][n-8*O]
__global__ __launch_bounds__(256) void pack_b_kernel(const float* __restrict__ W,
                                                     const float* __restrict__ root,
                                                     unsigned short* __restrict__ Bt, int O) {
    int i = blockIdx.x * 256 + threadIdx.x;
    int NTOT = 9 * O;
    if (i >= NTOT * 128) return;
    int k = i & 127, n = i >> 7;
    float v = (n < 8 * O) ? W[(size_t)(n / O) * 128 * O + (size_t)k * O + (n % O)]
                          : root[(size_t)k * O + (n - 8 * O)];
    Bt[(size_t)n * 128 + k] = f2h(v);
}

// ---------- fp16 MFMA GEMM: C[M,LDC] = A[M,128] @ Bt[LDC,128]^T, fp16 out ----------
// 64x64 tile, K=128 (2 chunks of 64), 4 waves in 2x2 grid.
template <int LDC>
__global__ __launch_bounds__(256) void gemm_xw(const unsigned short* __restrict__ A,
                                               const unsigned short* __restrict__ Bt,
                                               unsigned short* __restrict__ C) {
    __shared__ __align__(16) unsigned short As[64 * 64];
    __shared__ __align__(16) unsigned short Bs[64 * 64];
    const int t = threadIdx.x;
    const int w = t >> 6, lane = t & 63;
    const int q = lane >> 4, m = lane & 15;
    const int wr = w >> 1, wc = w & 1;     // 2x2 wave grid: 32x32 per wave
    const int bm = blockIdx.y * 64;
    const int bn = blockIdx.x * 64;

    f32x4 acc[2][2];
#pragma unroll
    for (int mb = 0; mb < 2; ++mb)
#pragma unroll
        for (int nb = 0; nb < 2; ++nb) acc[mb][nb] = (f32x4)0.f;

    const int srow = lane >> 3, schk = lane & 7;   // lane -> (row-in-8, 16B chunk)

#pragma unroll
    for (int kc = 0; kc < 2; ++kc) {
        const int k0 = kc * 64;
        // A tile: 64 rows x 64 fp16 (8 KB)
#pragma unroll
        for (int ii = 0; ii < 2; ++ii) {
            int i = w * 2 + ii;
            int grow = bm + i * 8 + srow;
            if (grow >= NN) grow = NN - 1;
            const unsigned short* g = A + (size_t)grow * 128 + k0 + schk * 8;
            __builtin_amdgcn_global_load_lds((gvoid_t*)g, (svoid_t*)(As + i * 512), 16, 0, 0);
        }
        // B tile: 64 rows of Bt x 64 fp16
#pragma unroll
        for (int ii = 0; ii < 2; ++ii) {
            int i = w * 2 + ii;
            const unsigned short* g = Bt + (size_t)(bn + i * 8 + srow) * 128 + k0 + schk * 8;
            __builtin_amdgcn_global_load_lds((gvoid_t*)g, (svoid_t*)(Bs + i * 512), 16, 0, 0);
        }
        __syncthreads();
#pragma unroll
        for (int s = 0; s < 2; ++s) {
            half8 af[2], bf[2];
#pragma unroll
            for (int mb = 0; mb < 2; ++mb)
                af[mb] = __builtin_bit_cast(half8,
                    *(const short8*)(As + (wr * 32 + mb * 16 + m) * 64 + s * 32 + q * 8));
#pragma unroll
            for (int nb = 0; nb < 2; ++nb)
                bf[nb] = __builtin_bit_cast(half8,
                    *(const short8*)(Bs + (wc * 32 + nb * 16 + m) * 64 + s * 32 + q * 8));
#pragma unroll
            for (int mb = 0; mb < 2; ++mb)
#pragma unroll
                for (int nb = 0; nb < 2; ++nb)
                    acc[mb][nb] = __builtin_amdgcn_mfma_f32_16x16x32_f16(af[mb], bf[nb],
                                                                         acc[mb][nb], 0, 0, 0);
        }
        __syncthreads();
    }

    // epilogue: C/D layout col=lane&15, row=quad*4+reg
#pragma unroll
    for (int mb = 0; mb < 2; ++mb)
#pragma unroll
        for (int nb = 0; nb < 2; ++nb) {
            int col = bn + wc * 32 + nb * 16 + m;
#pragma unroll
            for (int j = 0; j < 4; ++j) {
                int grow = bm + wr * 32 + mb * 16 + q * 4 + j;
                if (grow < NN)
                    C[(size_t)grow * LDC + col] = f2h(acc[mb][nb][j]);
            }
        }
}

// ---------- aggregation over transformed messages: one wave per dst ----------
// O=128: h[dst] = sum_e half2(XW[src_e, r_e*128 + 2*lane..]) * inv[dst,r_e]
//                 + XW[dst, 1024..] + bias  -> fp16 h1b
// O=64, FINAL: scalar per lane + sigmoid -> fp32 out
template <int O, bool FINAL>
__global__ __launch_bounds__(256) void agg_kernel(const int* __restrict__ rp,
                                                  const int* __restrict__ srcrel,
                                                  const float* __restrict__ inv,
                                                  const unsigned short* __restrict__ XW,
                                                  const float* __restrict__ bias,
                                                  void* __restrict__ Hout) {
    __shared__ float sinv[4][8];
    const int slot = threadIdx.x >> 6, lane = threadIdx.x & 63;
    const int w = blockIdx.x * 4 + slot;
    if (w >= NN) return;
    if (lane < 8) sinv[slot][lane] = inv[w * NR + lane];   // wave-synchronous, no barrier

    const int beg = rp[w * NR], end = rp[w * NR + NR];
    constexpr int LDC2 = 9 * O / 2;          // row stride in half2 units (576 or 288)

    if (O == 128) {
        const unsigned int* X2 = (const unsigned int*)XW;   // half2 units
        float2 acc = make_float2(0.f, 0.f);
        int i = beg;
        for (; i + 3 < end; i += 4) {        // 4 gathers in flight
            int p0 = srcrel[i], p1 = srcrel[i + 1], p2 = srcrel[i + 2], p3 = srcrel[i + 3];
            unsigned g0 = X2[(size_t)(p0 & 0xFFFFF) * LDC2 + (((unsigned)p0) >> 20) * 64 + lane];
            unsigned g1 = X2[(size_t)(p1 & 0xFFFFF) * LDC2 + (((unsigned)p1) >> 20) * 64 + lane];
            unsigned g2 = X2[(size_t)(p2 & 0xFFFFF) * LDC2 + (((unsigned)p2) >> 20) * 64 + lane];
            unsigned g3 = X2[(size_t)(p3 & 0xFFFFF) * LDC2 + (((unsigned)p3) >> 20) * 64 + lane];
            float s0 = sinv[slot][((unsigned)p0) >> 20];
            float s1 = sinv[slot][((unsigned)p1) >> 20];
            float s2 = sinv[slot][((unsigned)p2) >> 20];
            float s3 = sinv[slot][((unsigned)p3) >> 20];
            acc.x += h2f((unsigned short)(g0 & 0xFFFFu)) * s0;
            acc.y += h2f((unsigned short)(g0 >> 16)) * s0;
            acc.x += h2f((unsigned short)(g1 & 0xFFFFu)) * s1;
            acc.y += h2f((unsigned short)(g1 >> 16)) * s1;
            acc.x += h2f((unsigned short)(g2 & 0xFFFFu)) * s2;
            acc.y += h2f((unsigned short)(g2 >> 16)) * s2;
            acc.x += h2f((unsigned short)(g3 & 0xFFFFu)) * s3;
            acc.y += h2f((unsigned short)(g3 >> 16)) * s3;
        }
        for (; i < end; ++i) {
            int p0 = srcrel[i];
            unsigned g0 = X2[(size_t)(p0 & 0xFFFFF) * LDC2 + (((unsigned)p0) >> 20) * 64 + lane];
            float s0 = sinv[slot][((unsigned)p0) >> 20];
            acc.x += h2f((unsigned short)(g0 & 0xFFFFu)) * s0;
            acc.y += h2f((unsigned short)(g0 >> 16)) * s0;
        }
        // root block (cols 1024..1151 = half2 512..575) + bias
        unsigned rt = X2[(size_t)w * LDC2 + 512 + lane];
        float2 bv = ((const float2*)bias)[lane];
        float vx = acc.x + h2f((unsigned short)(rt & 0xFFFFu)) + bv.x;
        float vy = acc.y + h2f((unsigned short)(rt >> 16)) + bv.y;
        ((unsigned int*)Hout)[(size_t)w * 64 + lane] =
            (unsigned)f2h(vx) | ((unsigned)f2h(vy) << 16);
    } else {
        constexpr int LDC = 9 * O;           // 576
        float acc = 0.f;
        int i = beg;
        for (; i + 3 < end; i += 4) {
            int p0 = srcrel[i], p1 = srcrel[i + 1], p2 = srcrel[i + 2], p3 = srcrel[i + 3];
            unsigned short g0 = XW[(size_t)(p0 & 0xFFFFF) * LDC + (((unsigned)p0) >> 20) * 64 + lane];
            unsigned short g1 = XW[(size_t)(p1 & 0xFFFFF) * LDC + (((unsigned)p1) >> 20) * 64 + lane];
            unsigned short g2 = XW[(size_t)(p2 & 0xFFFFF) * LDC + (((unsigned)p2) >> 20) * 64 + lane];
            unsigned short g3 = XW[(size_t)(p3 & 0xFFFFF) * LDC + (((unsigned)p3) >> 20) * 64 + lane];
            acc += h2f(g0) * sinv[slot][((unsigned)p0) >> 20];
            acc += h2f(g1) * sinv[slot][((unsigned)p1) >> 20];
            acc += h2f(g2) * sinv[slot][((unsigned)p2) >> 20];
            acc += h2f(g3) * sinv[slot][((unsigned)p3) >> 20];
        }
        for (; i < end; ++i) {
            int p0 = srcrel[i];
            unsigned short g0 = XW[(size_t)(p0 & 0xFFFFF) * LDC + (((unsigned)p0) >> 20) * 64 + lane];
            acc += h2f(g0) * sinv[slot][((unsigned)p0) >> 20];
        }
        float v = acc + h2f(XW[(size_t)w * LDC + 512 + lane]) + bias[lane];
        ((float*)Hout)[(size_t)w * 64 + lane] = 1.f / (1.f + __expf(-v));
    }
}

extern "C" void kernel_launch(void* const* d_in, const int* in_sizes, int n_in,
                              void* d_out, int out_size, void* d_ws, size_t ws_size,
                              hipStream_t stream) {
    const float* x     = (const float*)d_in[0];
    const int*   esrc  = (const int*)d_in[1];
    const int*   edst  = (const int*)d_in[2];
    const int*   etyp  = (const int*)d_in[3];
    const float* W1    = (const float*)d_in[4];
    const float* root1 = (const float*)d_in[5];
    const float* b1    = (const float*)d_in[6];
    const float* W2    = (const float*)d_in[7];
    const float* root2 = (const float*)d_in[8];
    const float* b2    = (const float*)d_in[9];
    float* out = (float*)d_out;

    char* ws = (char*)d_ws;
    unsigned short* Bt1    = (unsigned short*)ws; ws += (size_t)1152 * 128 * 2; // 288 KB
    unsigned short* Bt2    = (unsigned short*)ws; ws += (size_t)576 * 128 * 2;  // 144 KB
    int*            cnt    = (int*)ws;            ws += (size_t)SCAN_N * 4;     // 1.6 MB
    float*          inv    = (float*)ws;          ws += (size_t)SCAN_N * 4;     // 1.6 MB
    int*            rp     = (int*)ws;            ws += (size_t)(SCAN_N + 64) * 4;
    int*            start  = (int*)ws;            ws += (size_t)SCAN_N * 4;     // 1.6 MB
    int*            bsum   = (int*)ws;            ws += (size_t)256 * 4;
    int*            boff   = (int*)ws;            ws += (size_t)257 * 4;
    int*            srcrel = (int*)ws;            ws += (size_t)NE * 4;         // 2.56 MB
    unsigned short* xh     = (unsigned short*)ws; ws += (size_t)NN * 128 * 2;   // 12.8 MB
    unsigned short* h1b    = (unsigned short*)ws; ws += (size_t)NN * 128 * 2;   // 12.8 MB
    unsigned short* xW     = (unsigned short*)ws;                               // 115.2 MB
    unsigned short* xW2    = xW;   // layer-2 transform aliases (xW dead after agg1)

    // CSR by (dst, rel) — hierarchical scan, fully parallel
    hipMemsetAsync(cnt, 0, (size_t)SCAN_N * 4, stream);
    count_kernel<<<(NE + 255) / 256, 256, 0, stream>>>(edst, etyp, cnt, NE);
    inv_kernel<<<(SCAN_N + 255) / 256, 256, 0, stream>>>(cnt, inv, SCAN_N);
    scan1_kernel<<<SCAN_NB, 256, 0, stream>>>(cnt, rp, bsum);
    scan2_kernel<<<1, 256, 0, stream>>>(bsum, boff, SCAN_NB);
    scan3_kernel<<<SCAN_NB, 256, 0, stream>>>(rp, start, boff, SCAN_NB);
    fill_kernel<<<(NE + 255) / 256, 256, 0, stream>>>(esrc, edst, etyp, start, srcrel, NE);

    // fp16 conversions / packs
    cvt_kernel<<<(NN * 32 + 255) / 256, 256, 0, stream>>>(x, xh, NN * 32);
    pack_b_kernel<<<(1152 * 128 + 255) / 256, 256, 0, stream>>>(W1, root1, Bt1, 128);
    pack_b_kernel<<<(576 * 128 + 255) / 256, 256, 0, stream>>>(W2, root2, Bt2, 64);

    const int agrid = (NN + 3) / 4;            // one wave per dst, 4 waves/block
    const int gy = (NN + 63) / 64;             // 64-row GEMM tiles

    // layer 1: transform xh -> xW [NN,1152], aggregate (+root+bias) -> h1b fp16
    gemm_xw<1152><<<dim3(1152 / 64, gy), 256, 0, stream>>>(xh, Bt1, xW);
    agg_kernel<128, false><<<agrid, 256, 0, stream>>>(rp, srcrel, inv, xW, b1, h1b);

    // layer 2: transform h1b -> xW2 [NN,576], aggregate (+root+bias+sigmoid) -> out fp32
    gemm_xw<576><<<dim3(576 / 64, gy), 256, 0, stream>>>(h1b, Bt2, xW2);
    agg_kernel<64, true><<<agrid, 256, 0, stream>>>(rp, srcrel, inv, xW2, b2, out);
}